// Round 4
// baseline (1290.381 us; speedup 1.0000x reference)
//
#include <hip/hip_runtime.h>
#include <hip/hip_bf16.h>
#include <math.h>

#define S_LEN 2048
#define HID   1024
#define NH    16
#define HD    64
#define BATCH 2

typedef __bf16 bf16;
typedef __attribute__((ext_vector_type(4))) __bf16 bf16x4;
typedef __attribute__((ext_vector_type(8))) __bf16 bf16x8;
typedef __attribute__((ext_vector_type(4))) float f32x4;

// ---------------- fp32 -> bf16 conversion (one-shot, memory-bound) ----------
__global__ __launch_bounds__(256) void cvt_f32_bf16(
    const float* __restrict__ src, bf16* __restrict__ dst, int n)
{
    int stride = gridDim.x * 256 * 4;
    for (int i = (blockIdx.x * 256 + threadIdx.x) * 4; i < n; i += stride) {
        float4 v = *(const float4*)(src + i);
        bf16x4 o;
        o[0] = (bf16)v.x; o[1] = (bf16)v.y; o[2] = (bf16)v.z; o[3] = (bf16)v.w;
        *(bf16x4*)(dst + i) = o;
    }
}

// ---------------- RoPE cos/sin table: tab[sp][d] = (cos, sin), d in [0,32) --
// Written into the first 512 KB of the `out` region of d_out (scratch): it is
// consumed only by the Q/K GEMMs, and `out` is fully overwritten by the final
// projection GEMM afterwards. Keeps d_ws usage at exactly 40 MB.
__global__ __launch_bounds__(256) void rope_tab(float2* __restrict__ tab)
{
    int i = blockIdx.x * 256 + threadIdx.x;  // 2048*32 entries
    int sp = i >> 5, d = i & 31;
    float f = (float)sp * exp2f(-(float)d * (13.287712379549449f / 32.0f));
    float sn, cs;
    sincosf(f, &sn, &cs);
    tab[i] = make_float2(cs, sn);
}

// ---------------- bf16 MFMA GEMM: C = A @ W^T ------------------------------
// A: (M,K) bf16 row-major, W: (N,K) bf16 row-major. fp32 accumulate.
// 128x128 tile, BK=64, 512 threads (8 waves, 2Mx4N), 16x16x32 MFMA.
// LDS XOR-8 swizzle applied via pre-swizzled GLOBAL source (linear LDS dest,
// required by global_load_lds), same XOR on the ds_read side.
// MODE 0: fp32 write C[m*N+n]                     (output projection)
// MODE 1: RoPE + transposed bf16 write (B,NH,S,HD) (Q, K)
// MODE 2: transposed bf16 write (B,NH,S,HD)        (V)
#define BM 128
#define BN 128
#define BK 64

__device__ __forceinline__ void gload_lds16(const void* g, void* l) {
    __builtin_amdgcn_global_load_lds(
        (__attribute__((address_space(1))) void*)g,
        (__attribute__((address_space(3))) void*)l, 16, 0, 0);
}

template <int MODE>
__global__ __launch_bounds__(512) void gemm_bf16(
    const bf16* __restrict__ A, const bf16* __restrict__ W,
    void* __restrict__ Cout, const float2* __restrict__ rope,
    int M, int N, int K)
{
    __shared__ bf16 As[BM * BK];   // 16 KB, row stride 64 bf16 = 128 B
    __shared__ bf16 Bs[BN * BK];   // 16 KB

    const int tid  = threadIdx.x;
    const int lane = tid & 63;
    const int w    = tid >> 6;     // 0..7
    const int wr   = w >> 2;       // 0..1  (64-row band)
    const int wc   = w & 3;        // 0..3
    const int m0   = blockIdx.x * BM;
    const int n0   = blockIdx.y * BN;
    const int fr   = lane & 15;    // fragment row
    const int fq   = lane >> 4;    // quad (k-chunk selector)
    // wave col base: covers {nb, nb+32} so a thread holds both RoPE halves
    const int nb   = ((wc >> 1) << 6) + ((wc & 1) << 4);

    // ---- staging addresses (2 x 16B per thread per tile, A and B) ----
    // chunk g stored at LDS chunk g ^ (row&7)  <=>  source pre-swizzle
    const int i0 = tid, i1 = tid + 512;
    const int r0 = i0 >> 3, c0 = i0 & 7, g0 = c0 ^ (r0 & 7);
    const int r1 = i1 >> 3, c1 = i1 & 7, g1 = c1 ^ (r1 & 7);
    const bf16* Ag0 = A + (size_t)(m0 + r0) * K + g0 * 8;
    const bf16* Ag1 = A + (size_t)(m0 + r1) * K + g1 * 8;
    const bf16* Wg0 = W + (size_t)(n0 + r0) * K + g0 * 8;
    const bf16* Wg1 = W + (size_t)(n0 + r1) * K + g1 * 8;
    bf16* Al0 = As + i0 * 8;
    bf16* Al1 = As + i1 * 8;
    bf16* Bl0 = Bs + i0 * 8;
    bf16* Bl1 = Bs + i1 * 8;
    const char* As_b = (const char*)As;
    const char* Bs_b = (const char*)Bs;

    f32x4 acc[4][2];
    #pragma unroll
    for (int mi = 0; mi < 4; ++mi)
        #pragma unroll
        for (int nj = 0; nj < 2; ++nj)
            acc[mi][nj] = (f32x4){0.f, 0.f, 0.f, 0.f};

    for (int k0 = 0; k0 < K; k0 += BK) {
        gload_lds16(Ag0 + k0, Al0);
        gload_lds16(Ag1 + k0, Al1);
        gload_lds16(Wg0 + k0, Bl0);
        gload_lds16(Wg1 + k0, Bl1);
        asm volatile("s_waitcnt vmcnt(0)" ::: "memory");
        __syncthreads();

        bf16x8 af[4][2], bw[2][2];
        #pragma unroll
        for (int mi = 0; mi < 4; ++mi) {
            int mrow = wr * 64 + mi * 16 + fr;
            #pragma unroll
            for (int kk = 0; kk < 2; ++kk) {
                int ch = (kk * 4 + fq) ^ (mrow & 7);
                af[mi][kk] = *(const bf16x8*)(As_b + mrow * 128 + ch * 16);
            }
        }
        #pragma unroll
        for (int nj = 0; nj < 2; ++nj) {
            int nrow = nb + nj * 32 + fr;
            #pragma unroll
            for (int kk = 0; kk < 2; ++kk) {
                int ch = (kk * 4 + fq) ^ (nrow & 7);
                bw[nj][kk] = *(const bf16x8*)(Bs_b + nrow * 128 + ch * 16);
            }
        }
        #pragma unroll
        for (int kk = 0; kk < 2; ++kk)
            #pragma unroll
            for (int mi = 0; mi < 4; ++mi)
                #pragma unroll
                for (int nj = 0; nj < 2; ++nj)
                    acc[mi][nj] = __builtin_amdgcn_mfma_f32_16x16x32_bf16(
                        af[mi][kk], bw[nj][kk], acc[mi][nj], 0, 0, 0);
        __syncthreads();
    }

    // ---- epilogue. C layout: col = lane&15, row = (lane>>4)*4 + r ----
    if (MODE == 0) {
        float* C = (float*)Cout;
        #pragma unroll
        for (int mi = 0; mi < 4; ++mi) {
            #pragma unroll
            for (int r = 0; r < 4; ++r) {
                int m = m0 + wr * 64 + mi * 16 + fq * 4 + r;
                #pragma unroll
                for (int nj = 0; nj < 2; ++nj) {
                    int n = n0 + nb + nj * 32 + fr;
                    C[(size_t)m * N + n] = acc[mi][nj][r];
                }
            }
        }
    } else {
        bf16* C = (bf16*)Cout;
        const int h = (n0 >> 6) + (wc >> 1);     // head (64-col span per wave)
        const int dlo = ((wc & 1) << 4) + fr;    // d in [0,32) for MODE 1
        #pragma unroll
        for (int mi = 0; mi < 4; ++mi) {
            #pragma unroll
            for (int r = 0; r < 4; ++r) {
                int m  = m0 + wr * 64 + mi * 16 + fq * 4 + r;
                int b  = m >> 11;           // / S_LEN
                int sp = m & (S_LEN - 1);   // % S_LEN
                size_t base = (((size_t)b * NH + h) * S_LEN + sp) * HD;
                if (MODE == 2) {
                    #pragma unroll
                    for (int nj = 0; nj < 2; ++nj)
                        C[base + dlo + nj * 32] = (bf16)acc[mi][nj][r];
                } else {  // MODE 1: RoPE pair (dlo, dlo+32)
                    float2 t = rope[(size_t)sp * 32 + dlo];
                    float lo = acc[mi][0][r], hi = acc[mi][1][r];
                    C[base + dlo]      = (bf16)(lo * t.x - hi * t.y);
                    C[base + dlo + 32] = (bf16)(hi * t.x + lo * t.y);
                }
            }
        }
    }
}

// ---------------- MFMA attention (unchanged, verified; Ho now bf16) --------
// Block: 256 threads (4 waves). One block handles a 16-row q-tile for one bh.
// LDS: fp32 scores [16][2052] (+pad vs bank conflicts), ~132 KB total.
#define SC_PITCH 2052

__global__ __launch_bounds__(256) void attn_mfma(
    const bf16* __restrict__ Qt, const bf16* __restrict__ Kt,
    const bf16* __restrict__ Vt, const float* __restrict__ bias,
    const int* __restrict__ mask, float* __restrict__ attn,
    bf16* __restrict__ ho)
{
    extern __shared__ char smem[];
    float* sc     = (float*)smem;                 // [16][SC_PITCH]
    float* red    = sc + 16 * SC_PITCH;           // [256]
    float* rowmax = red + 256;                    // [16]
    float* invl   = rowmax + 16;                  // [16]

    const int tid  = threadIdx.x;
    const int lane = tid & 63;
    const int w    = tid >> 6;
    const int n    = lane & 15;      // MFMA "lane&15" index
    const int quad = lane >> 4;

    const int qt = 127 - blockIdx.x;       // reversed for load balance
    const int bh = blockIdx.y;
    const int b  = bh >> 4, h = bh & 15;
    const int q0 = qt * 16;
    const int ncols = q0 + 16;             // valid score region [0, ncols)
    const int T = qt + 1;                  // number of 16-wide k tiles

    // ---- Q fragments (same 16 q rows for all waves) ----
    const bf16* qbase = Qt + ((size_t)bh * S_LEN + q0 + n) * HD + quad * 8;
    bf16x8 qf0 = *(const bf16x8*)(qbase);
    bf16x8 qf1 = *(const bf16x8*)(qbase + 32);

    const int* mrow = mask + b * S_LEN;

    // ---- Phase 1: scores via MFMA, scatter to LDS with bias+mask ----
    for (int t = w; t < T; t += 4) {
        int k0 = t * 16;
        int krow = k0 + n;
        const bf16* kbase = Kt + ((size_t)bh * S_LEN + krow) * HD + quad * 8;
        bf16x8 b0 = *(const bf16x8*)(kbase);
        bf16x8 b1 = *(const bf16x8*)(kbase + 32);
        f32x4 c = {0.f, 0.f, 0.f, 0.f};
        c = __builtin_amdgcn_mfma_f32_16x16x32_bf16(qf0, b0, c, 0, 0, 0);
        c = __builtin_amdgcn_mfma_f32_16x16x32_bf16(qf1, b1, c, 0, 0, 0);
        int mk = mrow[krow];
        #pragma unroll
        for (int r = 0; r < 4; ++r) {
            int qr = quad * 4 + r;          // local q row (C layout)
            int qabs = q0 + qr;
            float s = c[r] * 0.125f + bias[(size_t)qabs * S_LEN + krow];
            if (krow > qabs || mk == 0) s = -3.0e38f;
            sc[qr * SC_PITCH + krow] = s;
        }
    }
    __syncthreads();

    // ---- Phase 2: row max ----
    {
        const int r = tid & 15, s_id = tid >> 4;
        float lmax = -3.0e38f;
        for (int c = s_id; c < ncols; c += 16)
            lmax = fmaxf(lmax, sc[r * SC_PITCH + c]);
        red[tid] = lmax;
        __syncthreads();
        #pragma unroll
        for (int st = 128; st >= 16; st >>= 1) {
            if (tid < st) red[tid] = fmaxf(red[tid], red[tid + st]);
            __syncthreads();
        }
        if (tid < 16) rowmax[tid] = red[tid];
        __syncthreads();

        // ---- Phase 3: exp in place + row sum ----
        float mx = rowmax[r];
        float lsum = 0.f;
        for (int c = s_id; c < ncols; c += 16) {
            float p = __expf(sc[r * SC_PITCH + c] - mx);
            sc[r * SC_PITCH + c] = p;
            lsum += p;
        }
        red[tid] = lsum;
        __syncthreads();
        #pragma unroll
        for (int st = 128; st >= 16; st >>= 1) {
            if (tid < st) red[tid] += red[tid + st];
            __syncthreads();
        }
        if (tid < 16) invl[tid] = 1.0f / red[tid];
        __syncthreads();
    }

    // ---- Phase 4: write normalized attn rows (zeros past ncols) ----
    for (int r2 = 0; r2 < 16; ++r2) {
        float iv = invl[r2];
        float* arow = attn + ((size_t)bh * S_LEN + q0 + r2) * S_LEN;
        for (int c = tid * 4; c < S_LEN; c += 1024) {
            float4 o;
            if (c < ncols) {
                const float* s4 = sc + r2 * SC_PITCH + c;
                o.x = s4[0] * iv; o.y = s4[1] * iv;
                o.z = s4[2] * iv; o.w = s4[3] * iv;
            } else {
                o.x = o.y = o.z = o.w = 0.f;
            }
            *(float4*)(arow + c) = o;
        }
    }

    // ---- Phase 5: PV via MFMA; wave w handles dims [w*16, w*16+16) ----
    {
        const int d = w * 16 + n;
        const int m = n;  // A-operand q row = lane&15
        f32x4 acc0 = {0.f, 0.f, 0.f, 0.f};
        f32x4 acc1 = {0.f, 0.f, 0.f, 0.f};
        int toggle = 0;
        for (int kc = 0; kc < ncols; kc += 32, toggle ^= 1) {
            bf16x8 af, vf;
            #pragma unroll
            for (int j = 0; j < 8; ++j) {
                int k = kc + quad * 8 + j;
                float pv = (k < ncols) ? sc[m * SC_PITCH + k] : 0.f;
                af[j] = (bf16)pv;
                vf[j] = Vt[((size_t)bh * S_LEN + k) * HD + d];  // k < S_LEN always
            }
            if (toggle == 0)
                acc0 = __builtin_amdgcn_mfma_f32_16x16x32_bf16(af, vf, acc0, 0, 0, 0);
            else
                acc1 = __builtin_amdgcn_mfma_f32_16x16x32_bf16(af, vf, acc1, 0, 0, 0);
        }
        #pragma unroll
        for (int r = 0; r < 4; ++r) {
            int qr = quad * 4 + r;
            float o = (acc0[r] + acc1[r]) * invl[qr];
            ho[((size_t)(b * S_LEN + q0 + qr)) * HID + h * HD + d] = (bf16)o;
        }
    }
}

extern "C" void kernel_launch(void* const* d_in, const int* in_sizes, int n_in,
                              void* d_out, int out_size, void* d_ws, size_t ws_size,
                              hipStream_t stream) {
    const float* x     = (const float*)d_in[0];
    const int*   mask  = (const int*)d_in[1];
    const float* Wq    = (const float*)d_in[2];
    const float* Wk    = (const float*)d_in[3];
    const float* Wv    = (const float*)d_in[4];
    const float* Wo    = (const float*)d_in[5];
    const float* cbias = (const float*)d_in[6];

    float* out  = (float*)d_out;
    float* attn = out + (size_t)BATCH * S_LEN * HID;

    const size_t QKV = (size_t)BATCH * S_LEN * HID;  // 4,194,304
    const size_t WEL = (size_t)HID * HID;            // 1,048,576
    // d_ws layout (40.0 MB total — matches the previously-verified footprint):
    bf16* Qt  = (bf16*)d_ws;     //  8 MB
    bf16* Kt  = Qt + QKV;        //  8 MB
    bf16* Vt  = Kt + QKV;        //  8 MB
    bf16* Xb  = Vt + QKV;        //  8 MB (x in bf16; reused as Ho after QKV)
    bf16* Wqb = Xb + QKV;        //  2 MB
    bf16* Wkb = Wqb + WEL;       //  2 MB
    bf16* Wvb = Wkb + WEL;       //  2 MB
    bf16* Wob = Wvb + WEL;       //  2 MB
    bf16* Ho  = Xb;              // alias — x no longer needed post-QKV
    // rope table lives in `out` scratch: consumed by Q/K GEMMs, then `out`
    // is fully overwritten by the final projection GEMM.
    float2* rope = (float2*)out;  // 2048*32*8 B = 512 KB << 16 MB

    const int M = BATCH * S_LEN;  // 4096

    // one-shot conversions + RoPE table
    cvt_f32_bf16<<<2048, 256, 0, stream>>>(x, Xb, (int)QKV);
    cvt_f32_bf16<<<1024, 256, 0, stream>>>(Wq, Wqb, (int)WEL);
    cvt_f32_bf16<<<1024, 256, 0, stream>>>(Wk, Wkb, (int)WEL);
    cvt_f32_bf16<<<1024, 256, 0, stream>>>(Wv, Wvb, (int)WEL);
    cvt_f32_bf16<<<1024, 256, 0, stream>>>(Wo, Wob, (int)WEL);
    rope_tab<<<256, 256, 0, stream>>>(rope);

    dim3 g(M / BM, HID / BN), blk(512);
    gemm_bf16<1><<<g, blk, 0, stream>>>(Xb, Wqb, Qt, rope, M, HID, HID);
    gemm_bf16<1><<<g, blk, 0, stream>>>(Xb, Wkb, Kt, rope, M, HID, HID);
    gemm_bf16<2><<<g, blk, 0, stream>>>(Xb, Wvb, Vt, nullptr, M, HID, HID);

    const size_t lds_bytes = (16 * SC_PITCH + 256 + 32) * sizeof(float);
    static bool attr_set = false;
    if (!attr_set) {
        hipFuncSetAttribute((const void*)attn_mfma,
                            hipFuncAttributeMaxDynamicSharedMemorySize,
                            (int)lds_bytes);
        attr_set = true;
    }
    attn_mfma<<<dim3(S_LEN / 16, BATCH * NH), dim3(256), lds_bytes, stream>>>(
        Qt, Kt, Vt, cbias, mask, attn, Ho);

    gemm_bf16<0><<<g, blk, 0, stream>>>(Ho, Wob, out, nullptr, M, HID, HID);
}

// Round 11
// 1196.130 us; speedup vs baseline: 1.0788x; 1.0788x over previous
//
#include <hip/hip_runtime.h>
#include <hip/hip_bf16.h>
#include <math.h>

#define S_LEN 2048
#define HID   1024
#define NH    16
#define HD    64
#define BATCH 2

typedef __bf16 bf16;
typedef __attribute__((ext_vector_type(4))) __bf16 bf16x4;
typedef __attribute__((ext_vector_type(8))) __bf16 bf16x8;
typedef __attribute__((ext_vector_type(4))) float f32x4;

// ---------------- fp32 -> bf16 conversion (one-shot, memory-bound) ----------
__global__ __launch_bounds__(256) void cvt_f32_bf16(
    const float* __restrict__ src, bf16* __restrict__ dst, int n)
{
    int stride = gridDim.x * 256 * 4;
    for (int i = (blockIdx.x * 256 + threadIdx.x) * 4; i < n; i += stride) {
        float4 v = *(const float4*)(src + i);
        bf16x4 o;
        o[0] = (bf16)v.x; o[1] = (bf16)v.y; o[2] = (bf16)v.z; o[3] = (bf16)v.w;
        *(bf16x4*)(dst + i) = o;
    }
}

// ---------------- RoPE cos/sin table (lives in `out` scratch) ---------------
__global__ __launch_bounds__(256) void rope_tab(float2* __restrict__ tab)
{
    int i = blockIdx.x * 256 + threadIdx.x;  // 2048*32 entries
    int sp = i >> 5, d = i & 31;
    float f = (float)sp * exp2f(-(float)d * (13.287712379549449f / 32.0f));
    float sn, cs;
    sincosf(f, &sn, &cs);
    tab[i] = make_float2(cs, sn);
}

// ---------------- bf16 MFMA GEMM: C = A @ W^T ------------------------------
// MODE 0: fp32 write C[m*N+n]                      (output projection)
// MODE 1: RoPE + transposed bf16 write (B,NH,S,HD) (Q, K)
// MODE 2: TRANSPOSED V write (B,NH,HD,S) via scoped-LDS bounce (coalesced)
#define BM 128
#define BN 128
#define BK 64

__device__ __forceinline__ void gload_lds16(const void* g, void* l) {
    __builtin_amdgcn_global_load_lds(
        (__attribute__((address_space(1))) void*)g,
        (__attribute__((address_space(3))) void*)l, 16, 0, 0);
}

template <int MODE>
__global__ __launch_bounds__(512) void gemm_bf16(
    const bf16* __restrict__ A, const bf16* __restrict__ W,
    void* __restrict__ Cout, const float2* __restrict__ rope,
    int M, int N, int K)
{
    __shared__ bf16 As[BM * BK];   // 16 KB, row stride 64 bf16 = 128 B
    __shared__ bf16 Bs[BN * BK];   // 16 KB

    const int tid  = threadIdx.x;
    const int lane = tid & 63;
    const int w    = tid >> 6;     // 0..7
    const int wr   = w >> 2;       // 0..1  (64-row band)
    const int wc   = w & 3;        // 0..3
    const int m0   = blockIdx.x * BM;
    const int n0   = blockIdx.y * BN;
    const int fr   = lane & 15;    // fragment row
    const int fq   = lane >> 4;    // quad (k-chunk selector)
    const int nb   = ((wc >> 1) << 6) + ((wc & 1) << 4);

    // staging: chunk g stored at LDS chunk g ^ (row&7) via pre-swizzled source
    const int i0 = tid, i1 = tid + 512;
    const int r0 = i0 >> 3, c0 = i0 & 7, g0 = c0 ^ (r0 & 7);
    const int r1 = i1 >> 3, c1 = i1 & 7, g1 = c1 ^ (r1 & 7);
    const bf16* Ag0 = A + (size_t)(m0 + r0) * K + g0 * 8;
    const bf16* Ag1 = A + (size_t)(m0 + r1) * K + g1 * 8;
    const bf16* Wg0 = W + (size_t)(n0 + r0) * K + g0 * 8;
    const bf16* Wg1 = W + (size_t)(n0 + r1) * K + g1 * 8;
    bf16* Al0 = As + i0 * 8;
    bf16* Al1 = As + i1 * 8;
    bf16* Bl0 = Bs + i0 * 8;
    bf16* Bl1 = Bs + i1 * 8;
    const char* As_b = (const char*)As;
    const char* Bs_b = (const char*)Bs;

    f32x4 acc[4][2];
    #pragma unroll
    for (int mi = 0; mi < 4; ++mi)
        #pragma unroll
        for (int nj = 0; nj < 2; ++nj)
            acc[mi][nj] = (f32x4){0.f, 0.f, 0.f, 0.f};

    for (int k0 = 0; k0 < K; k0 += BK) {
        gload_lds16(Ag0 + k0, Al0);
        gload_lds16(Ag1 + k0, Al1);
        gload_lds16(Wg0 + k0, Bl0);
        gload_lds16(Wg1 + k0, Bl1);
        asm volatile("s_waitcnt vmcnt(0)" ::: "memory");
        __syncthreads();

        bf16x8 af[4][2], bw[2][2];
        #pragma unroll
        for (int mi = 0; mi < 4; ++mi) {
            int mrow = wr * 64 + mi * 16 + fr;
            #pragma unroll
            for (int kk = 0; kk < 2; ++kk) {
                int ch = (kk * 4 + fq) ^ (mrow & 7);
                af[mi][kk] = *(const bf16x8*)(As_b + mrow * 128 + ch * 16);
            }
        }
        #pragma unroll
        for (int nj = 0; nj < 2; ++nj) {
            int nrow = nb + nj * 32 + fr;
            #pragma unroll
            for (int kk = 0; kk < 2; ++kk) {
                int ch = (kk * 4 + fq) ^ (nrow & 7);
                bw[nj][kk] = *(const bf16x8*)(Bs_b + nrow * 128 + ch * 16);
            }
        }
        #pragma unroll
        for (int kk = 0; kk < 2; ++kk)
            #pragma unroll
            for (int mi = 0; mi < 4; ++mi)
                #pragma unroll
                for (int nj = 0; nj < 2; ++nj)
                    acc[mi][nj] = __builtin_amdgcn_mfma_f32_16x16x32_bf16(
                        af[mi][kk], bw[nj][kk], acc[mi][nj], 0, 0, 0);
        __syncthreads();
    }

    // ---- epilogue. C layout: col = lane&15, row = (lane>>4)*4 + r ----
    if constexpr (MODE == 0) {
        float* C = (float*)Cout;
        #pragma unroll
        for (int mi = 0; mi < 4; ++mi) {
            #pragma unroll
            for (int r = 0; r < 4; ++r) {
                int m = m0 + wr * 64 + mi * 16 + fq * 4 + r;
                #pragma unroll
                for (int nj = 0; nj < 2; ++nj) {
                    int n = n0 + nb + nj * 32 + fr;
                    C[(size_t)m * N + n] = acc[mi][nj][r];
                }
            }
        }
    } else if constexpr (MODE == 1) {
        bf16* C = (bf16*)Cout;
        const int h = (n0 >> 6) + (wc >> 1);     // head (64-col span per wave)
        const int dlo = ((wc & 1) << 4) + fr;    // d in [0,32)
        #pragma unroll
        for (int mi = 0; mi < 4; ++mi) {
            #pragma unroll
            for (int r = 0; r < 4; ++r) {
                int m  = m0 + wr * 64 + mi * 16 + fq * 4 + r;
                int b  = m >> 11;           // / S_LEN
                int sp = m & (S_LEN - 1);   // % S_LEN
                size_t base = (((size_t)b * NH + h) * S_LEN + sp) * HD;
                float2 t = rope[(size_t)sp * 32 + dlo];
                float lo = acc[mi][0][r], hi = acc[mi][1][r];
                C[base + dlo]      = (bf16)(lo * t.x - hi * t.y);
                C[base + dlo + 32] = (bf16)(hi * t.x + lo * t.y);
            }
        }
    } else {  // MODE 2: V^T (B,NH,HD,S) via dedicated LDS transpose bounce
        __shared__ __align__(16) bf16 sT[128 * 136];
        #pragma unroll
        for (int mi = 0; mi < 4; ++mi) {
            #pragma unroll
            for (int r = 0; r < 4; ++r) {
                int ml = wr * 64 + mi * 16 + fq * 4 + r;
                #pragma unroll
                for (int nj = 0; nj < 2; ++nj) {
                    int nl = nb + nj * 32 + fr;
                    sT[nl * 136 + ml] = (bf16)acc[mi][nj][r];
                }
            }
        }
        __syncthreads();
        int dl  = tid >> 2;            // 0..127 (n_local = feature)
        int seg = (tid & 3) * 32;      // sp segment
        int bb  = m0 >> 11;
        int spg = (m0 & (S_LEN - 1)) + seg;
        int hh  = (n0 >> 6) + (dl >> 6);
        int dd  = dl & 63;
        bf16* dst = (bf16*)Cout + ((size_t)(bb * NH + hh) * HD + dd) * S_LEN + spg;
        const bf16* srcp = sT + dl * 136 + seg;
        #pragma unroll
        for (int i = 0; i < 4; ++i)
            *(bf16x8*)(dst + i * 8) = *(const bf16x8*)(srcp + i * 8);
    }
}

// ---------------- MFMA attention (verified R4 structure; Phase 5 reads V^T) -
// Block: 256 threads (4 waves). One block handles a 16-row q-tile for one bh.
// LDS: fp32 scores [16][2052] (+pad vs bank conflicts), ~132 KB total.
#define SC_PITCH 2052

__global__ __launch_bounds__(256) void attn_mfma(
    const bf16* __restrict__ Qt, const bf16* __restrict__ Kt,
    const bf16* __restrict__ VT, const float* __restrict__ bias,
    const int* __restrict__ mask, float* __restrict__ attn,
    bf16* __restrict__ ho)
{
    extern __shared__ char smem[];
    float* sc     = (float*)smem;                 // [16][SC_PITCH]
    float* red    = sc + 16 * SC_PITCH;           // [256]
    float* rowmax = red + 256;                    // [16]
    float* invl   = rowmax + 16;                  // [16]

    const int tid  = threadIdx.x;
    const int lane = tid & 63;
    const int w    = tid >> 6;
    const int n    = lane & 15;      // MFMA "lane&15" index
    const int quad = lane >> 4;

    const int qt = 127 - blockIdx.x;       // reversed for load balance
    const int bh = blockIdx.y;
    const int b  = bh >> 4, h = bh & 15;
    const int q0 = qt * 16;
    const int ncols = q0 + 16;             // valid score region [0, ncols)
    const int T = qt + 1;                  // number of 16-wide k tiles

    // ---- Q fragments (same 16 q rows for all waves) ----
    const bf16* qbase = Qt + ((size_t)bh * S_LEN + q0 + n) * HD + quad * 8;
    bf16x8 qf0 = *(const bf16x8*)(qbase);
    bf16x8 qf1 = *(const bf16x8*)(qbase + 32);

    const int* mrow = mask + b * S_LEN;

    // ---- Phase 1: scores via MFMA, scatter to LDS with bias+mask ----
    for (int t = w; t < T; t += 4) {
        int k0 = t * 16;
        int krow = k0 + n;
        const bf16* kbase = Kt + ((size_t)bh * S_LEN + krow) * HD + quad * 8;
        bf16x8 b0 = *(const bf16x8*)(kbase);
        bf16x8 b1 = *(const bf16x8*)(kbase + 32);
        f32x4 c = {0.f, 0.f, 0.f, 0.f};
        c = __builtin_amdgcn_mfma_f32_16x16x32_bf16(qf0, b0, c, 0, 0, 0);
        c = __builtin_amdgcn_mfma_f32_16x16x32_bf16(qf1, b1, c, 0, 0, 0);
        int mk = mrow[krow];
        #pragma unroll
        for (int r = 0; r < 4; ++r) {
            int qr = quad * 4 + r;          // local q row (C layout)
            int qabs = q0 + qr;
            float s = c[r] * 0.125f + bias[(size_t)qabs * S_LEN + krow];
            if (krow > qabs || mk == 0) s = -3.0e38f;
            sc[qr * SC_PITCH + krow] = s;
        }
    }
    __syncthreads();

    // ---- Phase 2: row max ----
    {
        const int r = tid & 15, s_id = tid >> 4;
        float lmax = -3.0e38f;
        for (int c = s_id; c < ncols; c += 16)
            lmax = fmaxf(lmax, sc[r * SC_PITCH + c]);
        red[tid] = lmax;
        __syncthreads();
        #pragma unroll
        for (int st = 128; st >= 16; st >>= 1) {
            if (tid < st) red[tid] = fmaxf(red[tid], red[tid + st]);
            __syncthreads();
        }
        if (tid < 16) rowmax[tid] = red[tid];
        __syncthreads();

        // ---- Phase 3: exp in place + row sum ----
        float mx = rowmax[r];
        float lsum = 0.f;
        for (int c = s_id; c < ncols; c += 16) {
            float p = __expf(sc[r * SC_PITCH + c] - mx);
            sc[r * SC_PITCH + c] = p;
            lsum += p;
        }
        red[tid] = lsum;
        __syncthreads();
        #pragma unroll
        for (int st = 128; st >= 16; st >>= 1) {
            if (tid < st) red[tid] += red[tid + st];
            __syncthreads();
        }
        if (tid < 16) invl[tid] = 1.0f / red[tid];
        __syncthreads();
    }

    // ---- Phase 4: write normalized attn rows (zeros past ncols) ----
    for (int r2 = 0; r2 < 16; ++r2) {
        float iv = invl[r2];
        float* arow = attn + ((size_t)bh * S_LEN + q0 + r2) * S_LEN;
        for (int c = tid * 4; c < S_LEN; c += 1024) {
            float4 o;
            if (c < ncols) {
                const float* s4 = sc + r2 * SC_PITCH + c;
                o.x = s4[0] * iv; o.y = s4[1] * iv;
                o.z = s4[2] * iv; o.w = s4[3] * iv;
            } else {
                o.x = o.y = o.z = o.w = 0.f;
            }
            *(float4*)(arow + c) = o;
        }
    }

    // ---- Phase 5: PV via MFMA; wave w handles dims [w*16, w*16+16) ----
    // ONLY change vs verified: vf is one bf16x8 vector load from V^T
    // (B,NH,HD,S) instead of 8 scalar loads from (B,NH,S,HD).
    {
        const int d = w * 16 + n;
        const int m = n;  // A-operand q row = lane&15
        const bf16* vrow = VT + ((size_t)bh * HD + d) * S_LEN;
        f32x4 acc0 = {0.f, 0.f, 0.f, 0.f};
        f32x4 acc1 = {0.f, 0.f, 0.f, 0.f};
        int toggle = 0;
        for (int kc = 0; kc < ncols; kc += 32, toggle ^= 1) {
            bf16x8 af;
            bf16x8 vf = *(const bf16x8*)(vrow + kc + quad * 8);
            #pragma unroll
            for (int j = 0; j < 8; ++j) {
                int k = kc + quad * 8 + j;
                float pv = (k < ncols) ? sc[m * SC_PITCH + k] : 0.f;
                af[j] = (bf16)pv;
            }
            if (toggle == 0)
                acc0 = __builtin_amdgcn_mfma_f32_16x16x32_bf16(af, vf, acc0, 0, 0, 0);
            else
                acc1 = __builtin_amdgcn_mfma_f32_16x16x32_bf16(af, vf, acc1, 0, 0, 0);
        }
        #pragma unroll
        for (int r = 0; r < 4; ++r) {
            int qr = quad * 4 + r;
            float o = (acc0[r] + acc1[r]) * invl[qr];
            ho[((size_t)(b * S_LEN + q0 + qr)) * HID + h * HD + d] = (bf16)o;
        }
    }
}

extern "C" void kernel_launch(void* const* d_in, const int* in_sizes, int n_in,
                              void* d_out, int out_size, void* d_ws, size_t ws_size,
                              hipStream_t stream) {
    const float* x     = (const float*)d_in[0];
    const int*   mask  = (const int*)d_in[1];
    const float* Wq    = (const float*)d_in[2];
    const float* Wk    = (const float*)d_in[3];
    const float* Wv    = (const float*)d_in[4];
    const float* Wo    = (const float*)d_in[5];
    const float* cbias = (const float*)d_in[6];

    float* out  = (float*)d_out;
    float* attn = out + (size_t)BATCH * S_LEN * HID;

    const size_t QKV = (size_t)BATCH * S_LEN * HID;  // 4,194,304
    const size_t WEL = (size_t)HID * HID;            // 1,048,576
    // d_ws layout (40.0 MB total — verified footprint):
    bf16* Qt  = (bf16*)d_ws;     //  8 MB
    bf16* Kt  = Qt + QKV;        //  8 MB
    bf16* Vt  = Kt + QKV;        //  8 MB  (stored TRANSPOSED: B,NH,HD,S)
    bf16* Xb  = Vt + QKV;        //  8 MB (x in bf16; reused as Ho after QKV)
    bf16* Wqb = Xb + QKV;        //  2 MB
    bf16* Wkb = Wqb + WEL;       //  2 MB
    bf16* Wvb = Wkb + WEL;       //  2 MB
    bf16* Wob = Wvb + WEL;       //  2 MB
    bf16* Ho  = Xb;              // alias — x no longer needed post-QKV
    // rope table in `out` scratch (consumed by Q/K GEMMs, out overwritten later)
    float2* rope = (float2*)out;  // 512 KB << 16 MB

    const int M = BATCH * S_LEN;  // 4096

    cvt_f32_bf16<<<2048, 256, 0, stream>>>(x, Xb, (int)QKV);
    cvt_f32_bf16<<<1024, 256, 0, stream>>>(Wq, Wqb, (int)WEL);
    cvt_f32_bf16<<<1024, 256, 0, stream>>>(Wk, Wkb, (int)WEL);
    cvt_f32_bf16<<<1024, 256, 0, stream>>>(Wv, Wvb, (int)WEL);
    cvt_f32_bf16<<<1024, 256, 0, stream>>>(Wo, Wob, (int)WEL);
    rope_tab<<<256, 256, 0, stream>>>(rope);

    dim3 g(M / BM, HID / BN), blk(512);
    gemm_bf16<1><<<g, blk, 0, stream>>>(Xb, Wqb, Qt, rope, M, HID, HID);
    gemm_bf16<1><<<g, blk, 0, stream>>>(Xb, Wkb, Kt, rope, M, HID, HID);
    gemm_bf16<2><<<g, blk, 0, stream>>>(Xb, Wvb, Vt, nullptr, M, HID, HID);

    const size_t lds_bytes = (16 * SC_PITCH + 256 + 32) * sizeof(float);
    static bool attr_set = false;
    if (!attr_set) {
        hipFuncSetAttribute((const void*)attn_mfma,
                            hipFuncAttributeMaxDynamicSharedMemorySize,
                            (int)lds_bytes);
        attr_set = true;
    }
    attn_mfma<<<dim3(S_LEN / 16, BATCH * NH), dim3(256), lds_bytes, stream>>>(
        Qt, Kt, Vt, cbias, mask, attn, Ho);

    gemm_bf16<0><<<g, blk, 0, stream>>>(Ho, Wob, out, nullptr, M, HID, HID);
}